// Round 2
// 411.734 us; speedup vs baseline: 1.1650x; 1.1650x over previous
//
#include <hip/hip_runtime.h>

typedef _Float16 half8  __attribute__((ext_vector_type(8)));
typedef _Float16 half4v __attribute__((ext_vector_type(4)));
typedef float    floatx4 __attribute__((ext_vector_type(4)));

#define GLD_LDS16(g, l)                                                        \
  __builtin_amdgcn_global_load_lds(                                            \
      (const __attribute__((address_space(1))) void*)(g),                      \
      (__attribute__((address_space(3))) void*)(l), 16, 0, 0)

// Raw barrier / counted waits: no compiler-inserted vmcnt(0) drain
// (that drain is the documented ~20%+ stall of the old structure).
// Barrier via the BUILTIN (convergent intrinsic, matches the verified
// 8-phase template) — not inline asm.
#define SBAR() __builtin_amdgcn_s_barrier()
#define WAITVM2() asm volatile("s_waitcnt vmcnt(2)" ::: "memory")
#define WAITVM0() asm volatile("s_waitcnt vmcnt(0)" ::: "memory")
#define SCHED0() __builtin_amdgcn_sched_barrier(0)

// ---------------------------------------------------------------------------
// C = A * B^T GEMM, A:[M][K] lda, B:[N][K] ldb, f16 in, fp32 acc.
// 256x256 tile, BK=64, 8-phase counted-vmcnt schedule (T1..T5):
//   512 threads = 8 waves (2M x 4N), per-wave output 128x64, acc[8][4].
//   LDS 128 KiB: 2 buffers x {A 256x64, B 256x64} f16.
//   Per K-tile: 4 phases, each {ds_read frag subtile; issue 1 half-tile
//   global_load_lds prefetch (2 loads/thread); s_barrier; setprio(1);
//   16 x mfma_f32_16x16x32_f16; setprio(0); s_barrier}.
//   ONE s_waitcnt vmcnt(2) per K-tile (at phase 0, after issuing the first
//   prefetch of tile k+1): waits the 8 staging loads of tile k (issued
//   across tile k-1's phases), leaves the 2 newest in flight. Never drains
//   to 0 mid-loop (only the last tile). Publish is cross-wave correct:
//   every wave does its own vmcnt<=2 BEFORE the barrier, so after the
//   barrier all waves' tile-k staging has landed. Staging into buf[cur^1]
//   is safe: its last ds_reads were consumed by MFMAs before the previous
//   K-tile's trailing barrier.
//
// LDS layout: 16B chunk (row,kc) at slot row*8 + (kc ^ (row&7)) — XOR
// swizzle, 2-way max aliasing on ds_read_b128 (free), staging-compatible
// (linear LDS dest + pre-swizzled global source).
// C/D layout (16x16): col = lane&15, row = (lane>>4)*4 + reg  [m89/m91].
//
// XCD swizzle: 1D grid, xcd = bid&7.
//   EPI 0 (QKV): 768 blocks. j=bid>>3 in [0,96): n=(j&3), mi=(j>>2)&7,
//                z=j>>5. m-tile = xcd*8+mi -> each XCD owns rows
//                [2048*xcd, 2048*(xcd+1)) of xb.
//   EPI 2 (scores): 512 blocks. xcd = batch. j: m=j>>3, n=j&7.
//   EPI 3 (PV):     256 blocks. xcd = batch. j: m=j>>2, n=j&3.
//
// Fused softmax: EPI 2 stores p = exp2((s*scale-4)*log2e) f16 and
// atomicAdds per-row sums of the f16-rounded p; EPI 3 divides by rowsum.
// ---------------------------------------------------------------------------

// stage one half-tile (128 rows x 64 f16) of A or B into buffer c
#define STG_A(c, ht, ko)                                                       \
  do {                                                                         \
    GLD_LDS16(A0 + (size_t)(ht) * lda128 + (ko),                               \
              &lds[(c) * 32768 + ((ht) * 1024 + wid * 128) * 8]);              \
    GLD_LDS16(A1 + (size_t)(ht) * lda128 + (ko),                               \
              &lds[(c) * 32768 + ((ht) * 1024 + wid * 128 + 64) * 8]);         \
  } while (0)
#define STG_B(c, ht, ko)                                                       \
  do {                                                                         \
    GLD_LDS16(B0 + (size_t)(ht) * ldb128 + (ko),                               \
              &lds[(c) * 32768 + 16384 + ((ht) * 1024 + wid * 128) * 8]);      \
    GLD_LDS16(B1 + (size_t)(ht) * ldb128 + (ko),                               \
              &lds[(c) * 32768 + 16384 + ((ht) * 1024 + wid * 128 + 64) * 8]); \
  } while (0)

// fragment reads (plain loads: compiler tracks lgkmcnt for MFMA deps)
#define RDA(dst, c, mt, ks)                                                    \
  do {                                                                         \
    const int ra_ = wm + (mt) * 16 + lr;                                       \
    dst = *(const half8*)&lds[(c) * 32768 +                                    \
                              (ra_ * 8 + (((ks) * 4 + lk) ^ (ra_ & 7))) * 8];  \
  } while (0)
#define RDB(dst, c, nt, ks)                                                    \
  do {                                                                         \
    const int rb_ = wn + (nt) * 16 + lr;                                       \
    dst = *(const half8*)&lds[(c) * 32768 + 16384 +                            \
                              (rb_ * 8 + (((ks) * 4 + lk) ^ (rb_ & 7))) * 8];  \
  } while (0)

// 16 MFMA: C-quadrant (4 m-frags at MB.., 2 n-frags at NB..) x K=64
#define MM4x2(MB, NB, BF)                                                      \
  do {                                                                         \
    _Pragma("unroll") for (int mt_ = 0; mt_ < 4; ++mt_)                        \
        _Pragma("unroll") for (int n_ = 0; n_ < 2; ++n_)                       \
            _Pragma("unroll") for (int ks_ = 0; ks_ < 2; ++ks_)                \
                acc[(MB) + mt_][(NB) + n_] =                                   \
        __builtin_amdgcn_mfma_f32_16x16x32_f16(                                \
            af[mt_][ks_], BF[n_][ks_], acc[(MB) + mt_][(NB) + n_], 0, 0, 0);   \
  } while (0)

// one K-tile = 4 phases; CUR is a compile-time 0/1 (loop unrolled x2)
#define KBLOCK(CUR, KT)                                                        \
  do {                                                                         \
    const int ko_ = ((KT) + 1) << 6;                                           \
    const bool pf_ = ((KT) + 1 < NT);                                          \
    /* phase 0: wait tile KT staged; read A[0..3],B[0..1]; MFMA (m03,n01) */   \
    if (pf_) {                                                                 \
      STG_A(1 - (CUR), 0, ko_);                                                \
      WAITVM2();                                                               \
    } else {                                                                   \
      WAITVM0();                                                               \
    }                                                                          \
    SBAR();                                                                    \
    SCHED0();                                                                  \
    RDA(af[0][0], CUR, 0, 0); RDA(af[0][1], CUR, 0, 1);                        \
    RDA(af[1][0], CUR, 1, 0); RDA(af[1][1], CUR, 1, 1);                        \
    RDA(af[2][0], CUR, 2, 0); RDA(af[2][1], CUR, 2, 1);                        \
    RDA(af[3][0], CUR, 3, 0); RDA(af[3][1], CUR, 3, 1);                        \
    RDB(bf0[0][0], CUR, 0, 0); RDB(bf0[0][1], CUR, 0, 1);                      \
    RDB(bf0[1][0], CUR, 1, 0); RDB(bf0[1][1], CUR, 1, 1);                      \
    SBAR();                                                                    \
    SCHED0();                                                                  \
    __builtin_amdgcn_s_setprio(1);                                             \
    MM4x2(0, 0, bf0);                                                          \
    __builtin_amdgcn_s_setprio(0);                                             \
    SBAR();                                                                    \
    /* phase 1: read B[2..3]; stage B-h0 of KT+1; MFMA (m03,n23) */            \
    RDB(bf1[0][0], CUR, 2, 0); RDB(bf1[0][1], CUR, 2, 1);                      \
    RDB(bf1[1][0], CUR, 3, 0); RDB(bf1[1][1], CUR, 3, 1);                      \
    if (pf_) STG_B(1 - (CUR), 0, ko_);                                         \
    SBAR();                                                                    \
    SCHED0();                                                                  \
    __builtin_amdgcn_s_setprio(1);                                             \
    MM4x2(0, 2, bf1);                                                          \
    __builtin_amdgcn_s_setprio(0);                                             \
    SBAR();                                                                    \
    /* phase 2: read A[4..7]; stage A-h1; MFMA (m47,n23) */                    \
    RDA(af[0][0], CUR, 4, 0); RDA(af[0][1], CUR, 4, 1);                        \
    RDA(af[1][0], CUR, 5, 0); RDA(af[1][1], CUR, 5, 1);                        \
    RDA(af[2][0], CUR, 6, 0); RDA(af[2][1], CUR, 6, 1);                        \
    RDA(af[3][0], CUR, 7, 0); RDA(af[3][1], CUR, 7, 1);                        \
    if (pf_) STG_A(1 - (CUR), 1, ko_);                                         \
    SBAR();                                                                    \
    SCHED0();                                                                  \
    __builtin_amdgcn_s_setprio(1);                                             \
    MM4x2(4, 2, bf1);                                                          \
    __builtin_amdgcn_s_setprio(0);                                             \
    SBAR();                                                                    \
    /* phase 3: stage B-h1; MFMA (m47,n01) — bf0 still live in regs */         \
    if (pf_) STG_B(1 - (CUR), 1, ko_);                                         \
    SBAR();                                                                    \
    SCHED0();                                                                  \
    __builtin_amdgcn_s_setprio(1);                                             \
    MM4x2(4, 0, bf0);                                                          \
    __builtin_amdgcn_s_setprio(0);                                             \
    SBAR();                                                                    \
  } while (0)

template <int EPI>
__global__ __launch_bounds__(512, 2) void gemm_bt(
    const _Float16* __restrict__ A, const _Float16* __restrict__ B,
    void* __restrict__ Cv, void* __restrict__ Cv2, int lda, int ldb, int ldc,
    int kdim, long long sAz, long long sBz, long long sCz,
    const float* __restrict__ b0, const float* __restrict__ b1,
    const float* __restrict__ b2, float* __restrict__ rowsum, float scale) {
  __shared__ _Float16 lds[65536];  // 128 KiB: [2 buf][A 16384 | B 16384]

  const int bid = blockIdx.x;
  int z, m0, n0;
  if (EPI == 0) {
    const int xcd = bid & 7, j = bid >> 3;  // j in [0,96)
    z = j >> 5;
    m0 = (xcd * 8 + ((j >> 2) & 7)) * 256;
    n0 = (j & 3) * 256;
  } else if (EPI == 2) {
    z = bid & 7;
    const int j = bid >> 3;  // [0,64)
    m0 = (j >> 3) * 256;
    n0 = (j & 7) * 256;
  } else {
    z = bid & 7;
    const int j = bid >> 3;  // [0,32)
    m0 = (j >> 2) * 256;
    n0 = (j & 3) * 256;
  }

  A += (size_t)z * sAz;
  B += (size_t)z * sBz;

  const int tid = threadIdx.x;
  const int wid = tid >> 6;
  const int lane = tid & 63;
  const int wm = (wid & 1) * 128;   // wave m offset within 256 tile
  const int wn = (wid >> 1) * 64;   // wave n offset within 256 tile
  const int lr = lane & 15;
  const int lk = lane >> 4;

  floatx4 acc[8][4];
#pragma unroll
  for (int i = 0; i < 8; ++i)
#pragma unroll
    for (int j = 0; j < 4; ++j)
#pragma unroll
      for (int r = 0; r < 4; ++r) acc[i][j][r] = 0.f;

  // Staging addresses. Half-tile = 128 rows x 64 f16 = 1024 16B chunks;
  // 512 threads x 2 chunks. Chunk id s = wid*128 + i*64 + lane;
  // row = s>>3, source k-chunk = (s&7) ^ (row&7)  (XOR pre-swizzle).
  const int s0 = wid * 128 + lane;
  const int s1 = s0 + 64;
  const int r0 = s0 >> 3, c0 = (s0 & 7) ^ (r0 & 7);
  const int r1 = s1 >> 3, c1 = (s1 & 7) ^ (r1 & 7);
  const _Float16* A0 = A + (size_t)(m0 + r0) * lda + c0 * 8;
  const _Float16* A1 = A + (size_t)(m0 + r1) * lda + c1 * 8;
  const _Float16* B0 = B + (size_t)(n0 + r0) * ldb + c0 * 8;
  const _Float16* B1 = B + (size_t)(n0 + r1) * ldb + c1 * 8;
  const size_t lda128 = (size_t)lda * 128;
  const size_t ldb128 = (size_t)ldb * 128;

  const int NT = kdim >> 6;  // K-tiles (16 or 32; always even)

  // prologue: stage tile 0 into buf 0, drain, barrier
  STG_A(0, 0, 0);
  STG_B(0, 0, 0);
  STG_A(0, 1, 0);
  STG_B(0, 1, 0);
  WAITVM0();
  SBAR();

  half8 af[4][2], bf0[2][2], bf1[2][2];

  for (int kt = 0; kt < NT; kt += 2) {
    KBLOCK(0, kt);
    KBLOCK(1, kt + 1);
  }

  if (EPI == 0) {
    const float* bias = (z == 0) ? b0 : ((z == 1) ? b1 : b2);
#pragma unroll
    for (int mt = 0; mt < 8; ++mt) {
#pragma unroll
      for (int nt = 0; nt < 4; ++nt) {
#pragma unroll
        for (int r = 0; r < 4; ++r) {
          const int gm = m0 + wm + mt * 16 + lk * 4 + r;
          const int gn = n0 + wn + nt * 16 + lr;
          const float v = acc[mt][nt][r] + bias[gn];
          if (z < 2) {  // Q / K row-major f16
            ((_Float16*)Cv)[(size_t)z * 16777216 + (size_t)gm * 1024 + gn] =
                (_Float16)v;
          } else {  // V^T[b][d][s] f16
            const int b = gm >> 11, sseq = gm & 2047;
            ((_Float16*)Cv2)[(size_t)b * 2097152 + (size_t)gn * 2048 + sseq] =
                (_Float16)v;
          }
        }
      }
    }
  } else if (EPI == 2) {
    // p = exp2(s*scale*log2e - 4*log2e); store f16, atomic row-sum of
    // f16-rounded p (numerator and denominator use identical values).
    const float c1 = scale * 1.44269504f;
    const float c0e = -5.77078016f;  // -4 * log2(e)
    _Float16* Sout = (_Float16*)Cv + (size_t)z * sCz;
    float* rs = rowsum + z * 2048;
#pragma unroll
    for (int mt = 0; mt < 8; ++mt) {
#pragma unroll
      for (int r = 0; r < 4; ++r) {
        const int gm = m0 + wm + mt * 16 + lk * 4 + r;
        float part = 0.f;
#pragma unroll
        for (int nt = 0; nt < 4; ++nt) {
          const int gn = n0 + wn + nt * 16 + lr;
          const float p = exp2f(fmaf(acc[mt][nt][r], c1, c0e));
          const _Float16 ph = (_Float16)p;
          Sout[(size_t)gm * ldc + gn] = ph;
          part += (float)ph;
        }
#pragma unroll
        for (int o = 1; o < 16; o <<= 1) part += __shfl_xor(part, o);
        if (lr == 0) atomicAdd(&rs[gm], part);
      }
    }
  } else {
    float* O = (float*)Cv + (size_t)z * sCz;
    const float* rs = rowsum + z * 2048;
#pragma unroll
    for (int mt = 0; mt < 8; ++mt) {
#pragma unroll
      for (int r = 0; r < 4; ++r) {
        const int gm = m0 + wm + mt * 16 + lk * 4 + r;
        const float inv = 1.0f / rs[gm];
#pragma unroll
        for (int nt = 0; nt < 4; ++nt) {
          const int gn = n0 + wn + nt * 16 + lr;
          O[(size_t)gm * ldc + gn] = acc[mt][nt][r] * inv;
        }
      }
    }
  }
}

// ---------------------------------------------------------------------------
// Combined prep: blocks [0,16384) convert x fp32->f16 (4 elem/thread);
// blocks [16384,19456) transpose-convert W[h][d] fp32 -> Wt[d][h] f16.
// ---------------------------------------------------------------------------
__global__ __launch_bounds__(256) void prep(
    const float* __restrict__ x, _Float16* __restrict__ xb,
    const float* __restrict__ W0, const float* __restrict__ W1,
    const float* __restrict__ W2, _Float16* __restrict__ Wt) {
  const int bid = blockIdx.x;
  const int tid = threadIdx.x;
  if (bid < 16384) {
    const int i = bid * 256 + tid;
    const float4 v = ((const float4*)x)[i];
    half4v h;
    h[0] = (_Float16)v.x;
    h[1] = (_Float16)v.y;
    h[2] = (_Float16)v.z;
    h[3] = (_Float16)v.w;
    ((half4v*)xb)[i] = h;
    return;
  }
  __shared__ float tile[32][33];
  const int q = bid - 16384;
  const int bz = q >> 10;  // which matrix
  const int t = q & 1023;
  const int d0 = (t & 31) * 32, h0 = (t >> 5) * 32;
  const float* W = bz == 0 ? W0 : (bz == 1 ? W1 : W2);
  _Float16* T = Wt + (size_t)bz * 1048576;
  const int tx = tid & 31, ty = tid >> 5;
#pragma unroll
  for (int i = 0; i < 4; ++i)
    tile[ty + i * 8][tx] = W[(size_t)(h0 + ty + i * 8) * 1024 + d0 + tx];
  __syncthreads();
#pragma unroll
  for (int i = 0; i < 4; ++i)
    T[(size_t)(d0 + ty + i * 8) * 1024 + h0 + tx] =
        (_Float16)tile[tx][ty + i * 8];
}

// ---------------------------------------------------------------------------
// inputs: x[8,2048,1024] f32, Wq[1024,1024], bq[1024], Wk, bk, Wv, bv
// out: [8,2048,1024] f32
// ws layout (bytes): xb f16 @0 (32M), Wt f16 @32M (6M), Q,K f16 @38M (64M),
//   Vt f16 [b][d][s] @102M (32M), S/P f16 @134M (64M) -> ~198M total.
// rowsum fp32 [8][2048] (64 KB) REUSES xb@0: xb is dead after the QKV
// dispatch; the memset is enqueued between QKV and scores (stream-ordered).
// ---------------------------------------------------------------------------
extern "C" void kernel_launch(void* const* d_in, const int* in_sizes, int n_in,
                              void* d_out, int out_size, void* d_ws,
                              size_t ws_size, hipStream_t stream) {
  const float* x = (const float*)d_in[0];
  const float* Wq = (const float*)d_in[1];
  const float* bq = (const float*)d_in[2];
  const float* Wk = (const float*)d_in[3];
  const float* bk = (const float*)d_in[4];
  const float* Wv = (const float*)d_in[5];
  const float* bv = (const float*)d_in[6];
  float* out = (float*)d_out;

  char* w = (char*)d_ws;
  _Float16* xb = (_Float16*)(w);
  _Float16* Wt = (_Float16*)(w + 33554432);
  _Float16* QK = (_Float16*)(w + 39845888);  // Q then K, 16777216 elems each
  _Float16* Vt = (_Float16*)(w + 106954752);
  _Float16* S = (_Float16*)(w + 140509184);
  float* rowsum = (float*)(w);  // overlays dead xb after QKV

  // 1) x -> f16 and W -> Wt[d][h] f16 (one dispatch)
  prep<<<19456, 256, 0, stream>>>(x, xb, Wq, Wk, Wv, Wt);
  // 2) merged QKV projection (XCD-swizzled): M=16384, N=1024, K=1024
  gemm_bt<0><<<768, 512, 0, stream>>>(xb, Wt, QK, Vt, 1024, 1024, 1024, 1024,
                                      0LL, 1048576LL, 0LL, bq, bk, bv, nullptr,
                                      1.f);
  // 3) zero rowsum (xb now dead)
  hipMemsetAsync(rowsum, 0, 8 * 2048 * sizeof(float), stream);
  // 4) P = exp((Q K^T)/32 - 4) + row sums; per batch M=N=2048, K=1024
  gemm_bt<2><<<512, 512, 0, stream>>>(QK, QK + 16777216, S, nullptr, 1024,
                                      1024, 2048, 1024, 2097152LL, 2097152LL,
                                      4194304LL, nullptr, nullptr, nullptr,
                                      rowsum, 0.03125f);
  // 5) out = (P @ Vt^T) / rowsum; per batch M=2048, N=1024, K=2048; fp32 out
  gemm_bt<3><<<256, 512, 0, stream>>>(S, Vt, out, nullptr, 2048, 2048, 1024,
                                      2048, 4194304LL, 2097152LL, 2097152LL,
                                      nullptr, nullptr, nullptr, rowsum, 1.f);

  (void)in_sizes;
  (void)n_in;
  (void)out_size;
  (void)ws_size;
}